// Round 1
// 340.146 us; speedup vs baseline: 1.0743x; 1.0743x over previous
//
#include <hip/hip_runtime.h>

#define FEAT_D 1024
#define TT 64          // t-tile (one wave's lanes span it)
#define TI 64          // i-chunk per block (split across blockIdx.y)
#define PITCH 68       // floats/row: 272B = 16B-aligned -> b128 LDS ops, balanced banks

__global__ __launch_bounds__(256)
void centroid_loss_partial(const float* __restrict__ centroids,
                           const int*   __restrict__ units,
                           const int*   __restrict__ unit_lengths,
                           const float* __restrict__ Cmat,
                           float*       __restrict__ partials,
                           float*       __restrict__ out_atomic,
                           int B, int T, int use_atomic)
{
    const int b     = blockIdx.z;
    const int chunk = blockIdx.y;
    const int t0    = blockIdx.x * TT;
    const int L     = unit_lengths[b];
    const int slot  = (b * gridDim.y + chunk) * gridDim.x + blockIdx.x;

    if (t0 >= L) {                      // uniform per block, before any barrier
        if (!use_atomic && threadIdx.x == 0) partials[slot] = 0.0f;
        return;
    }

    __shared__ __align__(16) float tile[TT * PITCH];
    __shared__ float wsum[4];

    const int tid  = threadIdx.x;
    const int lane = tid & 63;
    const int wave = tid >> 6;          // 0..3
    const int t    = t0 + lane;

    const float* cent_b  = centroids + (size_t)b * T * FEAT_D;
    const int*   units_b = units + (size_t)b * T;
    const int i0 = chunk * TI;

    // ---- stage one 64(t) x 64(i) centroid tile: coalesced float4, b128 LDS stores ----
    {
        const int ii4  = tid & 15;   // which float4 along i
        const int trow = tid >> 4;   // 16 t-rows per pass
        #pragma unroll
        for (int p = 0; p < 4; ++p) {
            const int tt = trow + p * 16;
            const float4 v = *(const float4*)(cent_b + (size_t)(t0 + tt) * FEAT_D + i0 + ii4 * 4);
            *(float4*)&tile[tt * PITCH + ii4 * 4] = v;
        }
    }
    __syncthreads();

    // ---- compute: lanes along t; wave handles 16 i-values; b128 LDS reads ----
    float acc = 0.0f;
    const int ibase = i0 + wave * 16;
    #pragma unroll
    for (int m = 0; m < 4; ++m) {
        const float4 a4 = *(const float4*)&tile[lane * PITCH + wave * 16 + m * 4];
        #pragma unroll
        for (int j = 0; j < 4; ++j) {
            const int i    = ibase + m * 4 + j;
            const int flat = i * L + t;              // <= 1023*4096+4095, fits int
            int r = flat >> 10;
            r = (r < T - 1) ? r : (T - 1);           // keep OOB (masked) lanes in-bounds
            const int c = flat & 1023;
            const int u = units_b[r];                // wave-near-uniform -> 1-2 lines
            const float cv = Cmat[u * FEAT_D + c];   // ~contiguous 256B per wave, L2-resident
            const float a  = (&a4.x)[j];
            acc += fabsf(a - cv);
        }
    }
    acc *= (t < L) ? 1.0f : 0.0f;       // mask once, not per element (values always finite)

    // ---- reduce: wave shuffle, then 4 partials via LDS, one store ----
    #pragma unroll
    for (int off = 32; off > 0; off >>= 1)
        acc += __shfl_down(acc, off, 64);
    if (lane == 0) wsum[wave] = acc;
    __syncthreads();
    if (tid == 0) {
        float s = (wsum[0] + wsum[1] + wsum[2] + wsum[3]) / ((float)L * (float)B);
        if (use_atomic) atomicAdd(out_atomic, s);
        else            partials[slot] = s;
    }
}

__global__ __launch_bounds__(256)
void reduce_partials(const float* __restrict__ partials,
                     float* __restrict__ out, int n4)
{
    float s = 0.0f;
    for (int idx = threadIdx.x; idx < n4; idx += 256) {
        const float4 v = ((const float4*)partials)[idx];
        s += (v.x + v.y) + (v.z + v.w);
    }
    #pragma unroll
    for (int off = 32; off > 0; off >>= 1)
        s += __shfl_down(s, off, 64);
    __shared__ float ws[4];
    const int lane = threadIdx.x & 63, wave = threadIdx.x >> 6;
    if (lane == 0) ws[wave] = s;
    __syncthreads();
    if (threadIdx.x == 0) out[0] = (ws[0] + ws[1]) + (ws[2] + ws[3]);
}

extern "C" void kernel_launch(void* const* d_in, const int* in_sizes, int n_in,
                              void* d_out, int out_size, void* d_ws, size_t ws_size,
                              hipStream_t stream) {
    const float* centroids    = (const float*)d_in[0];
    const int*   units        = (const int*)d_in[1];
    const int*   unit_lengths = (const int*)d_in[2];
    const float* Cmat         = (const float*)d_in[3];
    float* out = (float*)d_out;

    const int B = in_sizes[2];                 // 16
    const int T = in_sizes[1] / B;             // 4096

    const int ntile  = (T + TT - 1) / TT;      // 64
    const int nchunk = FEAT_D / TI;            // 16
    const int nslots = ntile * nchunk * B;     // 16384

    dim3 grid(ntile, nchunk, B);
    dim3 block(256);

    if (ws_size >= (size_t)nslots * sizeof(float)) {
        // partials-in-workspace path: no memset, no atomics, deterministic reduce
        float* partials = (float*)d_ws;
        centroid_loss_partial<<<grid, block, 0, stream>>>(centroids, units, unit_lengths,
                                                          Cmat, partials, out, B, T, 0);
        reduce_partials<<<1, block, 0, stream>>>(partials, out, nslots / 4);
    } else {
        // fallback: atomic accumulation (needs zeroed output)
        hipMemsetAsync(d_out, 0, sizeof(float), stream);
        centroid_loss_partial<<<grid, block, 0, stream>>>(centroids, units, unit_lengths,
                                                          Cmat, nullptr, out, B, T, 1);
    }
}